// Round 5
// baseline (48.618 us; speedup 1.0000x reference)
//
#include <hip/hip_runtime.h>

typedef float f32x4 __attribute__((ext_vector_type(4)));

// Exact floor(log2(x)) for x > 0, including denormals (used on block maxima only).
__device__ __forceinline__ int flog2_exact(float x) {
    unsigned b = __float_as_uint(x);
    int e = (int)((b >> 23) & 0xFFu);
    if (e == 0) {                       // denormal
        unsigned m = b & 0x7FFFFFu;
        return 31 - __clz(m) - 149;
    }
    return e - 127;
}

// sign(v) * floor(|v| + 0.5) — same fp32 ops as the reference
__device__ __forceinline__ float round_ref(float v) {
    return copysignf(floorf(fabsf(v) + 0.5f), v);
}

// Process one 4-block task (512 elems): lanes grouped 16/block, 8 elems/lane.
__device__ __forceinline__ void process_task(const f32x4 v0, const f32x4 v1,
                                             f32x4& r0, f32x4& r1) {
    float a[8] = {v0.x, v0.y, v0.z, v0.w, v1.x, v1.y, v1.z, v1.w};

    // one-pass fp64 stats over the 16-lane group (one 128-elem block)
    double s = 0.0, s2 = 0.0;
    #pragma unroll
    for (int i = 0; i < 8; ++i) {
        double d = (double)fabsf(a[i]);
        s += d;
        s2 = fma(d, d, s2);
    }
    #pragma unroll
    for (int off = 1; off < 16; off <<= 1) {
        s  += __shfl_xor(s, off);
        s2 += __shfl_xor(s2, off);
    }
    const double mean = s * (1.0 / 128.0);
    double var = fma(mean, -mean, s2 * (1.0 / 128.0));
    var = var < 0.0 ? 0.0 : var;
    const double v4 = 4.0 * var;       // (a-mean)^2 > 4*var  <=>  outlier

    // classify + group maxima
    bool o[8];
    float mi = 0.0f, mov = 0.0f;
    #pragma unroll
    for (int i = 0; i < 8; ++i) {
        double dd = (double)a[i] - mean;
        o[i] = fma(dd, dd, -v4) > 0.0;
        float ab = fabsf(a[i]);
        mi  = fmaxf(mi,  o[i] ? 0.0f : ab);
        mov = fmaxf(mov, o[i] ? ab : 0.0f);
    }
    #pragma unroll
    for (int off = 1; off < 16; off <<= 1) {
        mi  = fmaxf(mi,  __shfl_xor(mi, off));
        mov = fmaxf(mov, __shfl_xor(mov, off));
    }

    // shared exponents (exact integer math)
    int se_in = (mi == 0.0f) ? -126 : flog2_exact(mi);       // EMAX_IN = 0
    if (se_in < -127) se_in = -20;                           // SCALE_LO
    int se_out = ((mov == 0.0f) ? -126 : (flog2_exact(mov) + se_in)) - 8;
    if (se_out < -127) se_out = -20;
    const int d   = se_in - se_out;
    const int g_in = se_in - 4;                    // inlier grid exponent
    const float L_in  = ldexpf(31.0f, g_in);       // inlier clamp (exact)
    const float L_out = ldexpf(448.0f, -d);        // outlier clamp (exact)
    const int d3 = d + 3;

    // unified quantize: one chain per element
    #pragma unroll
    for (int i = 0; i < 8; ++i) {
        int e_a = (int)((__float_as_uint(a[i]) >> 23) & 0xFFu) - 127;
        int pe  = e_a + d;                 // = floor(log2|a * 2^d|) (exact)
        pe = pe < -6 ? -6 : pe;            // emin clamp
        int g = o[i] ? (pe - d3) : g_in;   // per-element grid exponent
        float r    = round_ref(ldexpf(a[i], -g));
        float outv = ldexpf(r, g);
        float L    = o[i] ? L_out : L_in;
        outv = fminf(fmaxf(outv, -L), L);
        if (i < 4) r0[i] = outv; else r1[i - 4] = outv;
    }
}

__global__ __launch_bounds__(256) void mxq_kernel(const f32x4* __restrict__ x,
                                                  f32x4* __restrict__ y,
                                                  int nsuper) { // super = 8 blocks = 1024 elems
    const int lane = threadIdx.x & 63;
    const int off0 = (lane >> 4) * 32 + (lane & 15);   // q*32 + l
    const int wid  = blockIdx.x * (blockDim.x >> 6) + (threadIdx.x >> 6);
    const int nw   = gridDim.x * (blockDim.x >> 6);

    int t = wid;
    f32x4 d0, d1, d2, d3;
    if (t < nsuper) {
        const size_t b = (size_t)t * 256 + off0;
        d0 = x[b]; d1 = x[b + 16]; d2 = x[b + 128]; d3 = x[b + 144];
    }
    while (t < nsuper) {
        const int tn = t + nw;
        f32x4 e0 = d0, e1 = d1, e2 = d2, e3 = d3;
        if (tn < nsuper) {                       // prefetch next supertask
            const size_t bn = (size_t)tn * 256 + off0;
            e0 = x[bn]; e1 = x[bn + 16]; e2 = x[bn + 128]; e3 = x[bn + 144];
        }

        // two independent tasks -> interleaved chains (ILP 2)
        f32x4 r0, r1, r2, r3;
        process_task(d0, d1, r0, r1);
        process_task(d2, d3, r2, r3);

        const size_t b = (size_t)t * 256 + off0;
        __builtin_nontemporal_store(r0, &y[b]);
        __builtin_nontemporal_store(r1, &y[b + 16]);
        __builtin_nontemporal_store(r2, &y[b + 128]);
        __builtin_nontemporal_store(r3, &y[b + 144]);

        d0 = e0; d1 = e1; d2 = e2; d3 = e3;
        t = tn;
    }
}

extern "C" void kernel_launch(void* const* d_in, const int* in_sizes, int n_in,
                              void* d_out, int out_size, void* d_ws, size_t ws_size,
                              hipStream_t stream) {
    const f32x4* x = (const f32x4*)d_in[0];
    f32x4* y = (f32x4*)d_out;
    int n = in_sizes[0];
    int nsuper = n / 1024;               // 32768 supertasks (8 blocks each)
    int threads = 256;
    int waves_per_wg = threads / 64;
    int grid = 2048;                     // 8192 waves -> 4 supertasks each
    int max_grid = (nsuper + waves_per_wg - 1) / waves_per_wg;
    if (grid > max_grid) grid = max_grid;
    mxq_kernel<<<grid, threads, 0, stream>>>(x, y, nsuper);
}

// Round 6
// 46.557 us; speedup vs baseline: 1.0443x; 1.0443x over previous
//
#include <hip/hip_runtime.h>

typedef float f32x4 __attribute__((ext_vector_type(4)));

// DPP controls: 16-lane group reduction = quad_perm xor1, xor2, row_ror:4, row_ror:8
#define DPP_X1 0xB1   // quad_perm [1,0,3,2]
#define DPP_X2 0x4E   // quad_perm [2,3,0,1]
#define DPP_R4 0x124  // row_ror:4
#define DPP_R8 0x128  // row_ror:8

template <int CTRL>
__device__ __forceinline__ float dpp_mv(float v) {
    return __int_as_float(__builtin_amdgcn_update_dpp(0, __float_as_int(v), CTRL, 0xF, 0xF, true));
}
template <int CTRL>
__device__ __forceinline__ double dpp_mv64(double v) {
    unsigned long long u = __double_as_longlong(v);
    int lo = __builtin_amdgcn_update_dpp(0, (int)(unsigned)(u & 0xFFFFFFFFull), CTRL, 0xF, 0xF, true);
    int hi = __builtin_amdgcn_update_dpp(0, (int)(unsigned)(u >> 32), CTRL, 0xF, 0xF, true);
    return __longlong_as_double(((unsigned long long)(unsigned)hi << 32) | (unsigned)lo);
}

// Exact floor(log2(x)) for x > 0, including denormals (block maxima only).
__device__ __forceinline__ int flog2_exact(float x) {
    unsigned b = __float_as_uint(x);
    int e = (int)((b >> 23) & 0xFFu);
    if (e == 0) {
        unsigned m = b & 0x7FFFFFu;
        return 31 - __clz(m) - 149;
    }
    return e - 127;
}

__global__ __launch_bounds__(256) void mxq_kernel(const f32x4* __restrict__ x,
                                                  f32x4* __restrict__ y,
                                                  int ntask) {  // task = 4 blocks = 512 elems
    const int lane = threadIdx.x & 63;
    const int off0 = (lane >> 4) * 32 + (lane & 15);   // q*32 + l
    const int wid  = blockIdx.x * (blockDim.x >> 6) + (threadIdx.x >> 6);
    const int nw   = gridDim.x * (blockDim.x >> 6);

    const f32x4* xp = x + (size_t)wid * 128 + off0;
    f32x4*       yp = y + (size_t)wid * 128 + off0;
    const size_t step = (size_t)nw * 128;

    for (int t = wid; t < ntask; t += nw, xp += step, yp += step) {
        const f32x4 v0 = xp[0];
        const f32x4 v1 = xp[16];
        float a[8] = {v0.x, v0.y, v0.z, v0.w, v1.x, v1.y, v1.z, v1.w};
        double ad[8];

        // ---- one-pass fp64 stats; single cvt per element, abs via modifier ----
        double s = 0.0, s2 = 0.0;
        #pragma unroll
        for (int i = 0; i < 8; ++i) {
            ad[i] = (double)a[i];
            s += fabs(ad[i]);                 // add_f64 with |src| modifier
            s2 = fma(ad[i], ad[i], s2);       // square is sign-free, exact
        }
        s += dpp_mv64<DPP_X1>(s);  s2 += dpp_mv64<DPP_X1>(s2);
        s += dpp_mv64<DPP_X2>(s);  s2 += dpp_mv64<DPP_X2>(s2);
        s += dpp_mv64<DPP_R4>(s);  s2 += dpp_mv64<DPP_R4>(s2);
        s += dpp_mv64<DPP_R8>(s);  s2 += dpp_mv64<DPP_R8>(s2);

        const double mean = s * (1.0 / 128.0);
        double var = fma(mean, -mean, s2 * (1.0 / 128.0));
        var = var < 0.0 ? 0.0 : var;
        const double v4 = 4.0 * var;          // (a-mean)^2 > 4*var <=> outlier

        // ---- classify + per-path maxima ----
        bool o[8];
        float mi = 0.0f, mov = 0.0f;
        #pragma unroll
        for (int i = 0; i < 8; ++i) {
            double dd = ad[i] - mean;
            o[i] = fma(dd, dd, -v4) > 0.0;
            float zi = o[i] ? 0.0f : a[i];
            float zo = o[i] ? a[i] : 0.0f;
            mi  = fmaxf(mi,  fabsf(zi));      // abs folds as modifier
            mov = fmaxf(mov, fabsf(zo));
        }
        mi = fmaxf(mi, dpp_mv<DPP_X1>(mi));  mov = fmaxf(mov, dpp_mv<DPP_X1>(mov));
        mi = fmaxf(mi, dpp_mv<DPP_X2>(mi));  mov = fmaxf(mov, dpp_mv<DPP_X2>(mov));
        mi = fmaxf(mi, dpp_mv<DPP_R4>(mi));  mov = fmaxf(mov, dpp_mv<DPP_R4>(mov));
        mi = fmaxf(mi, dpp_mv<DPP_R8>(mi));  mov = fmaxf(mov, dpp_mv<DPP_R8>(mov));

        // ---- shared exponents (exact integer math) ----
        int se_in = (mi == 0.0f) ? -126 : flog2_exact(mi);       // EMAX_IN = 0
        if (se_in < -127) se_in = -20;                           // SCALE_LO
        int se_out = ((mov == 0.0f) ? -126 : (flog2_exact(mov) + se_in)) - 8;
        if (se_out < -127) se_out = -20;
        const int d    = se_in - se_out;
        const int g_in = se_in - 4;
        const int m9   = -(d + 9);                     // lower bound on g_out
        const float L_in  = ldexpf(31.0f, g_in);       // exact clamp bounds
        const float L_out = ldexpf(448.0f, -d);

        // ---- unified quantize ----
        f32x4 r0, r1;
        #pragma unroll
        for (int i = 0; i < 8; ++i) {
            int eb = (int)((__float_as_uint(a[i]) >> 23) & 0xFFu);
            int g_out = max(eb - 130, m9);     // = clamp(pe,-6..) - 3 - d  (exact)
            int g = o[i] ? g_out : g_in;
            float t2 = ldexpf(a[i], -g);
            float r  = copysignf(truncf(fabsf(t2) + 0.5f), a[i]);  // round half away
            float outv = ldexpf(r, g);
            float L = o[i] ? L_out : L_in;
            outv = __builtin_amdgcn_fmed3f(outv, -L, L);           // clamp
            if (i < 4) r0[i] = outv; else r1[i - 4] = outv;
        }

        __builtin_nontemporal_store(r0, yp);
        __builtin_nontemporal_store(r1, yp + 16);
    }
}

extern "C" void kernel_launch(void* const* d_in, const int* in_sizes, int n_in,
                              void* d_out, int out_size, void* d_ws, size_t ws_size,
                              hipStream_t stream) {
    const f32x4* x = (const f32x4*)d_in[0];
    f32x4* y = (f32x4*)d_out;
    int n = in_sizes[0];
    int ntask = n / 512;                 // 65536 wave-tasks (4 blocks each)
    int threads = 256;
    int waves_per_wg = threads / 64;
    int grid = 2048;
    int max_grid = (ntask + waves_per_wg - 1) / waves_per_wg;
    if (grid > max_grid) grid = max_grid;
    mxq_kernel<<<grid, threads, 0, stream>>>(x, y, ntask);
}

// Round 7
// 46.119 us; speedup vs baseline: 1.0542x; 1.0095x over previous
//
#include <hip/hip_runtime.h>

typedef float f32x4 __attribute__((ext_vector_type(4)));

// DPP controls: 16-lane group reduction = quad_perm xor1, xor2, row_ror:4, row_ror:8
#define DPP_X1 0xB1   // quad_perm [1,0,3,2]
#define DPP_X2 0x4E   // quad_perm [2,3,0,1]
#define DPP_R4 0x124  // row_ror:4
#define DPP_R8 0x128  // row_ror:8

template <int CTRL>
__device__ __forceinline__ float dpp_mv(float v) {
    return __int_as_float(__builtin_amdgcn_update_dpp(0, __float_as_int(v), CTRL, 0xF, 0xF, true));
}
template <int CTRL>
__device__ __forceinline__ double dpp_mv64(double v) {
    unsigned long long u = __double_as_longlong(v);
    int lo = __builtin_amdgcn_update_dpp(0, (int)(unsigned)(u & 0xFFFFFFFFull), CTRL, 0xF, 0xF, true);
    int hi = __builtin_amdgcn_update_dpp(0, (int)(unsigned)(u >> 32), CTRL, 0xF, 0xF, true);
    return __longlong_as_double(((unsigned long long)(unsigned)hi << 32) | (unsigned)lo);
}

// Exact floor(log2(x)) for x > 0, including denormals (block maxima only).
__device__ __forceinline__ int flog2_exact(float x) {
    unsigned b = __float_as_uint(x);
    int e = (int)((b >> 23) & 0xFFu);
    if (e == 0) {
        unsigned m = b & 0x7FFFFFu;
        return 31 - __clz(m) - 149;
    }
    return e - 127;
}

__global__ __launch_bounds__(256) void mxq_kernel(const f32x4* __restrict__ x,
                                                  f32x4* __restrict__ y,
                                                  int ntask) {  // task = 4 blocks = 512 elems
    const int lane = threadIdx.x & 63;
    const int off0 = (lane >> 4) * 32 + (lane & 15);   // q*32 + l
    const int wid  = blockIdx.x * (blockDim.x >> 6) + (threadIdx.x >> 6);
    const int nw   = gridDim.x * (blockDim.x >> 6);

    const f32x4* xp = x + (size_t)wid * 128 + off0;
    f32x4*       yp = y + (size_t)wid * 128 + off0;
    const size_t step = (size_t)nw * 128;

    for (int t = wid; t < ntask; t += nw, xp += step, yp += step) {
        const f32x4 v0 = xp[0];
        const f32x4 v1 = xp[16];
        float a[8] = {v0.x, v0.y, v0.z, v0.w, v1.x, v1.y, v1.z, v1.w};
        double ad[8];

        // ---- one-pass fp64 stats; single cvt per element, abs via modifier ----
        double s = 0.0, s2 = 0.0;
        #pragma unroll
        for (int i = 0; i < 8; ++i) {
            ad[i] = (double)a[i];
            s += fabs(ad[i]);                 // add_f64 with |src| modifier
            s2 = fma(ad[i], ad[i], s2);       // square is sign-free, exact
        }
        s += dpp_mv64<DPP_X1>(s);  s2 += dpp_mv64<DPP_X1>(s2);
        s += dpp_mv64<DPP_X2>(s);  s2 += dpp_mv64<DPP_X2>(s2);
        s += dpp_mv64<DPP_R4>(s);  s2 += dpp_mv64<DPP_R4>(s2);
        s += dpp_mv64<DPP_R8>(s);  s2 += dpp_mv64<DPP_R8>(s2);

        const double mean = s * (1.0 / 128.0);
        double var = fma(mean, -mean, s2 * (1.0 / 128.0));
        var = var < 0.0 ? 0.0 : var;
        const double v4 = 4.0 * var;          // (a-mean)^2 > 4*var <=> outlier

        // ---- classify + per-path maxima ----
        bool o[8];
        float mi = 0.0f, mov = 0.0f;
        #pragma unroll
        for (int i = 0; i < 8; ++i) {
            double dd = ad[i] - mean;
            o[i] = fma(dd, dd, -v4) > 0.0;
            float zi = o[i] ? 0.0f : a[i];
            float zo = o[i] ? a[i] : 0.0f;
            mi  = fmaxf(mi,  fabsf(zi));      // abs folds as modifier
            mov = fmaxf(mov, fabsf(zo));
        }
        mi = fmaxf(mi, dpp_mv<DPP_X1>(mi));  mov = fmaxf(mov, dpp_mv<DPP_X1>(mov));
        mi = fmaxf(mi, dpp_mv<DPP_X2>(mi));  mov = fmaxf(mov, dpp_mv<DPP_X2>(mov));
        mi = fmaxf(mi, dpp_mv<DPP_R4>(mi));  mov = fmaxf(mov, dpp_mv<DPP_R4>(mov));
        mi = fmaxf(mi, dpp_mv<DPP_R8>(mi));  mov = fmaxf(mov, dpp_mv<DPP_R8>(mov));

        // ---- shared exponents (exact integer math) ----
        int se_in = (mi == 0.0f) ? -126 : flog2_exact(mi);       // EMAX_IN = 0
        if (se_in < -127) se_in = -20;                           // SCALE_LO
        int se_out = ((mov == 0.0f) ? -126 : (flog2_exact(mov) + se_in)) - 8;
        if (se_out < -127) se_out = -20;
        const int d    = se_in - se_out;
        const int g_in = se_in - 4;
        const int m9   = -(d + 9);                     // lower bound on g_out
        const float L_in  = ldexpf(31.0f, g_in);       // exact clamp bounds
        const float L_out = ldexpf(448.0f, -d);

        // ---- unified quantize ----
        f32x4 r0, r1;
        #pragma unroll
        for (int i = 0; i < 8; ++i) {
            int eb = (int)((__float_as_uint(a[i]) >> 23) & 0xFFu);
            int g_out = max(eb - 130, m9);     // = clamp(pe,-6..) - 3 - d  (exact)
            int g = o[i] ? g_out : g_in;
            float t2 = ldexpf(a[i], -g);
            float r  = copysignf(truncf(fabsf(t2) + 0.5f), a[i]);  // round half away
            float outv = ldexpf(r, g);
            float L = o[i] ? L_out : L_in;
            outv = __builtin_amdgcn_fmed3f(outv, -L, L);           // clamp
            if (i < 4) r0[i] = outv; else r1[i - 4] = outv;
        }

        yp[0]  = r0;        // plain stores: let output stay L2/L3-resident
        yp[16] = r1;
    }
}

extern "C" void kernel_launch(void* const* d_in, const int* in_sizes, int n_in,
                              void* d_out, int out_size, void* d_ws, size_t ws_size,
                              hipStream_t stream) {
    const f32x4* x = (const f32x4*)d_in[0];
    f32x4* y = (f32x4*)d_out;
    int n = in_sizes[0];
    int ntask = n / 512;                 // 65536 wave-tasks (4 blocks each)
    int threads = 256;
    int waves_per_wg = threads / 64;
    int grid = 2048;
    int max_grid = (ntask + waves_per_wg - 1) / waves_per_wg;
    if (grid > max_grid) grid = max_grid;
    mxq_kernel<<<grid, threads, 0, stream>>>(x, y, ntask);
}

// Round 8
// 44.515 us; speedup vs baseline: 1.0922x; 1.0360x over previous
//
#include <hip/hip_runtime.h>

typedef float f32x4 __attribute__((ext_vector_type(4)));

// DPP controls: 16-lane group reduction = quad_perm xor1, xor2, row_ror:4, row_ror:8
#define DPP_X1 0xB1   // quad_perm [1,0,3,2]
#define DPP_X2 0x4E   // quad_perm [2,3,0,1]
#define DPP_R4 0x124  // row_ror:4
#define DPP_R8 0x128  // row_ror:8

template <int CTRL>
__device__ __forceinline__ float dpp_mv(float v) {
    return __int_as_float(__builtin_amdgcn_update_dpp(0, __float_as_int(v), CTRL, 0xF, 0xF, true));
}
template <int CTRL>
__device__ __forceinline__ double dpp_mv64(double v) {
    unsigned long long u = __double_as_longlong(v);
    int lo = __builtin_amdgcn_update_dpp(0, (int)(unsigned)(u & 0xFFFFFFFFull), CTRL, 0xF, 0xF, true);
    int hi = __builtin_amdgcn_update_dpp(0, (int)(unsigned)(u >> 32), CTRL, 0xF, 0xF, true);
    return __longlong_as_double(((unsigned long long)(unsigned)hi << 32) | (unsigned)lo);
}

// Exact floor(log2(x)) for x > 0, including denormals (block maxima only).
__device__ __forceinline__ int flog2_exact(float x) {
    unsigned b = __float_as_uint(x);
    int e = (int)((b >> 23) & 0xFFu);
    if (e == 0) {
        unsigned m = b & 0x7FFFFFu;
        return 31 - __clz(m) - 149;
    }
    return e - 127;
}

__global__ __launch_bounds__(256) void mxq_kernel(const f32x4* __restrict__ x,
                                                  f32x4* __restrict__ y,
                                                  int ntask) {  // task = 4 blocks = 512 elems
    const int lane = threadIdx.x & 63;
    const int wid  = blockIdx.x * (blockDim.x >> 6) + (threadIdx.x >> 6);
    if (wid >= ntask) return;            // one task per wave: maximal wave churn

    const size_t base = (size_t)wid * 128 + (lane >> 4) * 32 + (lane & 15);
    const f32x4 v0 = x[base];
    const f32x4 v1 = x[base + 16];
    float a[8] = {v0.x, v0.y, v0.z, v0.w, v1.x, v1.y, v1.z, v1.w};
    double ad[8];

    // ---- one-pass fp64 stats; single cvt per element, abs via modifier ----
    double s = 0.0, s2 = 0.0;
    #pragma unroll
    for (int i = 0; i < 8; ++i) {
        ad[i] = (double)a[i];
        s += fabs(ad[i]);                 // add_f64 with |src| modifier
        s2 = fma(ad[i], ad[i], s2);       // square is sign-free, exact
    }
    s += dpp_mv64<DPP_X1>(s);  s2 += dpp_mv64<DPP_X1>(s2);
    s += dpp_mv64<DPP_X2>(s);  s2 += dpp_mv64<DPP_X2>(s2);
    s += dpp_mv64<DPP_R4>(s);  s2 += dpp_mv64<DPP_R4>(s2);
    s += dpp_mv64<DPP_R8>(s);  s2 += dpp_mv64<DPP_R8>(s2);

    const double mean = s * (1.0 / 128.0);
    double var = fma(mean, -mean, s2 * (1.0 / 128.0));
    var = var < 0.0 ? 0.0 : var;
    const double thr = 2.0 * sqrt(var);   // |a-mean| > 2*sigma  <=> outlier

    // ---- classify + per-path maxima (2 f64 ops/elem: sub, cmp|.|) ----
    bool o[8];
    float mi = 0.0f, mov = 0.0f;
    #pragma unroll
    for (int i = 0; i < 8; ++i) {
        o[i] = fabs(ad[i] - mean) > thr;
        float zi = o[i] ? 0.0f : a[i];
        float zo = o[i] ? a[i] : 0.0f;
        mi  = fmaxf(mi,  fabsf(zi));
        mov = fmaxf(mov, fabsf(zo));
    }
    mi = fmaxf(mi, dpp_mv<DPP_X1>(mi));  mov = fmaxf(mov, dpp_mv<DPP_X1>(mov));
    mi = fmaxf(mi, dpp_mv<DPP_X2>(mi));  mov = fmaxf(mov, dpp_mv<DPP_X2>(mov));
    mi = fmaxf(mi, dpp_mv<DPP_R4>(mi));  mov = fmaxf(mov, dpp_mv<DPP_R4>(mov));
    mi = fmaxf(mi, dpp_mv<DPP_R8>(mi));  mov = fmaxf(mov, dpp_mv<DPP_R8>(mov));

    // ---- shared exponents (exact integer math) ----
    int se_in = (mi == 0.0f) ? -126 : flog2_exact(mi);       // EMAX_IN = 0
    if (se_in < -127) se_in = -20;                           // SCALE_LO
    int se_out = ((mov == 0.0f) ? -126 : (flog2_exact(mov) + se_in)) - 8;
    if (se_out < -127) se_out = -20;
    const int d    = se_in - se_out;
    const int g_in = se_in - 4;
    const int m9   = -(d + 9);                     // lower bound on g_out
    const float L_in  = ldexpf(31.0f, g_in);       // exact clamp bounds
    const float L_out = ldexpf(448.0f, -d);

    // ---- unified quantize ----
    f32x4 r0, r1;
    #pragma unroll
    for (int i = 0; i < 8; ++i) {
        int eb = (int)((__float_as_uint(a[i]) >> 23) & 0xFFu);
        int g_out = max(eb - 130, m9);     // = clamp(pe,-6..) - 3 - d  (exact)
        int g = o[i] ? g_out : g_in;
        float t2 = ldexpf(a[i], -g);
        float r  = copysignf(truncf(fabsf(t2) + 0.5f), a[i]);  // round half away
        float outv = ldexpf(r, g);
        float L = o[i] ? L_out : L_in;
        outv = __builtin_amdgcn_fmed3f(outv, -L, L);           // clamp
        if (i < 4) r0[i] = outv; else r1[i - 4] = outv;
    }

    y[base]      = r0;
    y[base + 16] = r1;
}

extern "C" void kernel_launch(void* const* d_in, const int* in_sizes, int n_in,
                              void* d_out, int out_size, void* d_ws, size_t ws_size,
                              hipStream_t stream) {
    const f32x4* x = (const f32x4*)d_in[0];
    f32x4* y = (f32x4*)d_out;
    int n = in_sizes[0];
    int ntask = n / 512;                 // 65536 wave-tasks (4 blocks each)
    int threads = 256;
    int waves_per_wg = threads / 64;     // 4
    int grid = (ntask + waves_per_wg - 1) / waves_per_wg;   // 16384: 1 task/wave
    mxq_kernel<<<grid, threads, 0, stream>>>(x, y, ntask);
}